// Round 3
// baseline (206.626 us; speedup 1.0000x reference)
//
#include <hip/hip_runtime.h>

// PCE basis expansion: Phi[n,b] = prod_j polyval(xn[n,j], idxset[b,j])
// D=50, P=2 -> each basis row has <= 2 nonzero orders; polyval(_,0) == 1.
// Output 32768x1326 fp32 = 174 MB -> write-BW bound (~28 us floor).
//
// R2 redesign: flat float4 mapping (BN=4 rows/block = 21216 B region,
// 16B-aligned), per-float4 descriptor = int4 of 8 packed LDS word-indices
// with a non-affine bank-scatter permutation PERM(off)=off+(off>>2) baked in
// (breaks the stride-6 gather pattern that caused ~4-way conflicts).
// Inner loop per 16 B: 8 extracts + 8 ds_read_b32 (conflict-free) + 4 muls +
// 1 nontemporal dwordx4 store. R0/R1 (~90 us) were pipe-balanced with no
// headroom; this gives LDS/VALU 2x margin under the HBM write stream.

#define DD       50
#define P1       3
#define NBASIS   1326
#define BN       4
#define NQ       ((BN * NBASIS) / 4)   // 1326 float4 positions per block period
#define BLOCK    256
#define PVSTRIDE 192                   // per-row pv table stride (words)
#define PERM(o)  ((o) + ((o) >> 2))    // injective, max PERM(149)=186 < 192

typedef float vf4 __attribute__((ext_vector_type(4)));

// ---- Kernel A1: coalesced idxset -> compact (off0 | off1<<8) per basis row.
#define A1_ROWS 128
__global__ __launch_bounds__(BLOCK) void build_compact(
    const int* __restrict__ idxset, int* __restrict__ compact, int nbasis, int d)
{
    __shared__ int tile[A1_ROWS * DD];
    const int r0   = blockIdx.x * A1_ROWS;
    const int rows = min(A1_ROWS, nbasis - r0);
    for (int i = threadIdx.x; i < rows * d; i += BLOCK)
        tile[i] = idxset[(size_t)r0 * d + i];
    __syncthreads();
    const int r = threadIdx.x;
    if (r < rows) {
        const int* row = tile + r * d;
        int off0 = 0, off1 = 0, cnt = 0;
        for (int j = 0; j < d; ++j) {
            int o = row[j];
            if (o != 0) {
                int off = j * P1 + o;
                if (cnt == 0) off0 = off; else off1 = off;
                ++cnt;                  // total order <= 2 -> cnt <= 2
            }
        }
        compact[r0 + r] = off0 | (off1 << 8);
    }
}

// ---- Kernel A2: compact -> per-float4 descriptors (8 packed word-indices).
__global__ __launch_bounds__(BLOCK) void build_desc4(
    const int* __restrict__ compact, int4* __restrict__ desc4)
{
    int q = blockIdx.x * blockDim.x + threadIdx.x;
    if (q >= NQ) return;
    int w[4];
    #pragma unroll
    for (int k = 0; k < 4; ++k) {
        int f  = 4 * q + k;
        int rl = f / NBASIS;            // local row 0..BN-1
        int b  = f - rl * NBASIS;
        int cb = compact[b];
        int sA = rl * PVSTRIDE + PERM(cb & 0xff);
        int sB = rl * PVSTRIDE + PERM((cb >> 8) & 0xff);
        w[k] = sA | (sB << 16);
    }
    desc4[q] = make_int4(w[0], w[1], w[2], w[3]);
}

// ---- Main kernel.
#define EMIT(d, ptr) do {                                              \
    vf4 v;                                                             \
    v.x = s_pv[(d).x & 0xffff] * s_pv[((unsigned)(d).x) >> 16];        \
    v.y = s_pv[(d).y & 0xffff] * s_pv[((unsigned)(d).y) >> 16];        \
    v.z = s_pv[(d).z & 0xffff] * s_pv[((unsigned)(d).z) >> 16];        \
    v.w = s_pv[(d).w & 0xffff] * s_pv[((unsigned)(d).w) >> 16];        \
    __builtin_nontemporal_store(v, (vf4*)(ptr));                       \
} while (0)

__global__ __launch_bounds__(BLOCK, 4) void pce4_kernel(
    const float* __restrict__ x, const float* __restrict__ mean,
    const float* __restrict__ var, const float* __restrict__ basis,
    const int4* __restrict__ desc4, float* __restrict__ out)
{
    __shared__ float s_pv[BN * PVSTRIDE];   // 3 KB
    const int tid  = threadIdx.x;
    const int row0 = blockIdx.x * BN;

    // Preload descriptors (same for all blocks -> L2 broadcast).
    int4 d0 = desc4[tid];
    int4 d1 = desc4[tid + 256];
    int4 d2 = desc4[tid + 512];
    int4 d3 = desc4[tid + 768];
    int4 d4 = desc4[tid + 1024];
    const bool tail = (tid < NQ - 1280);    // 46
    int4 d5 = tail ? desc4[tid + 1280] : make_int4(0, 0, 0, 0);

    float b00 = basis[0], b01 = basis[1], b02 = basis[2];
    float b10 = basis[3], b11 = basis[4], b12 = basis[5];
    float b20 = basis[6], b21 = basis[7], b22 = basis[8];

    // Stage per-row pv tables; x reads are one coalesced 800 B segment.
    if (tid < BN * DD) {
        int r = tid / DD, c = tid - r * DD;
        float xv = (x[(size_t)row0 * DD + tid] - mean[c]) / var[c];
        float x2 = xv * xv;
        int base = r * PVSTRIDE;
        s_pv[base + PERM(P1 * c + 0)] = b00 + b01 * xv + b02 * x2;  // == 1.0
        s_pv[base + PERM(P1 * c + 1)] = b10 + b11 * xv + b12 * x2;
        s_pv[base + PERM(P1 * c + 2)] = b20 + b21 * xv + b22 * x2;
    }
    __syncthreads();

    vf4* obase = (vf4*)(out + (size_t)row0 * NBASIS);  // 21216*blockIdx % 16 == 0
    EMIT(d0, obase + tid);
    EMIT(d1, obase + tid + 256);
    EMIT(d2, obase + tid + 512);
    EMIT(d3, obase + tid + 768);
    EMIT(d4, obase + tid + 1024);
    if (tail) EMIT(d5, obase + tid + 1280);
}

extern "C" void kernel_launch(void* const* d_in, const int* in_sizes, int n_in,
                              void* d_out, int out_size, void* d_ws, size_t ws_size,
                              hipStream_t stream) {
    const float* x      = (const float*)d_in[0];
    const float* mean   = (const float*)d_in[1];
    const float* var    = (const float*)d_in[2];
    const float* basis  = (const float*)d_in[3];
    const int*   idxset = (const int*)d_in[4];
    float* out = (float*)d_out;

    const int d      = in_sizes[1];          // 50
    const int n      = in_sizes[0] / d;      // 32768
    const int nbasis = in_sizes[4] / d;      // 1326

    int*  compact = (int*)d_ws;                          // 1326 ints
    int4* desc4   = (int4*)((char*)d_ws + 8192);         // 1326 int4 = 21 KB

    build_compact<<<(nbasis + A1_ROWS - 1) / A1_ROWS, BLOCK, 0, stream>>>(
        idxset, compact, nbasis, d);
    build_desc4<<<(NQ + BLOCK - 1) / BLOCK, BLOCK, 0, stream>>>(compact, desc4);
    pce4_kernel<<<n / BN, BLOCK, 0, stream>>>(x, mean, var, basis, desc4, out);
}